// Round 4
// baseline (7118.220 us; speedup 1.0000x reference)
//
#include <hip/hip_runtime.h>
#include <stdint.h>

typedef unsigned short ushortT;
typedef __attribute__((ext_vector_type(8))) short short8;
typedef __attribute__((ext_vector_type(4))) float f32x4;

#define B_ 128
#define T_ 512
#define I_ 512
#define H_ 512
#define NG 1536     // 3*512 gate cols
#define NTOT 1544   // + 8 q cols

__device__ __forceinline__ float bf2f(ushortT u){
  union { unsigned int i; float f; } v; v.i = ((unsigned int)u) << 16; return v.f;
}
__device__ __forceinline__ ushortT f2bf(float f){           // RNE
  union { float f; unsigned int i; } v; v.f = f;
  unsigned int u = v.i;
  u += 0x7fffu + ((u >> 16) & 1u);
  return (ushortT)(u >> 16);
}
// truncating split: x == hi + lo to ~17 mantissa bits
__device__ __forceinline__ void splitf(float x, ushortT& hi, ushortT& lo){
  union { float f; unsigned int i; } v; v.f = x;
  hi = (ushortT)(v.i >> 16);
  union { unsigned int i; float f; } h; h.i = v.i & 0xffff0000u;
  union { float f; unsigned int i; } r; r.f = x - h.f;
  lo = (ushortT)(r.i >> 16);
}
__device__ __forceinline__ float sigf(float x){ return 1.f / (1.f + __expf(-x)); }
__device__ __forceinline__ float tanhfast(float x){
  float e = __expf(-2.f * fabsf(x));
  float t = (1.f - e) / (1.f + e);
  return copysignf(t, x);
}
__device__ __forceinline__ void stx(float* p, size_t i, float v){ p[i] = v; }
__device__ __forceinline__ void stx(ushortT* p, size_t i, float v){ p[i] = f2bf(v); }
__device__ __forceinline__ float ldx(const float* p, size_t i){ return p[i]; }
__device__ __forceinline__ float ldx(const ushortT* p, size_t i){ return bf2f(p[i]); }

// ---------------------------------------------------------------------------
// Kernel A (validated r3): weight prep. btx[n][k] = bf16(W*(k,n));
// bth_hi/lo[n][k] = hi/lo split of W*(512+k,n). n in [0,1544) = [Wi|Wg|Wo|Wf].
// ---------------------------------------------------------------------------
__global__ __launch_bounds__(256) void prep_w(
    const float* __restrict__ Wi, const float* __restrict__ Wg,
    const float* __restrict__ Wo, const float* __restrict__ Wf,
    ushortT* __restrict__ btx, ushortT* __restrict__ bth_hi,
    ushortT* __restrict__ bth_lo, int wlo)
{
  int e = blockIdx.x * 256 + threadIdx.x;   // 1544*512 = 3088*256
  int n = e >> 9;
  int k = e & 511;
  const float* W; int ld, c;
  if (n < 512){ W = Wi; ld = 512; c = n; }
  else if (n < 1024){ W = Wg; ld = 512; c = n - 512; }
  else if (n < 1536){ W = Wo; ld = 512; c = n - 1024; }
  else { W = Wf; ld = 8; c = n - 1536; }
  btx[e] = f2bf(W[(size_t)k * ld + c]);
  float wh = W[(size_t)(512 + k) * ld + c];
  ushortT hi, lo; splitf(wh, hi, lo);
  bth_hi[e] = hi;
  if (wlo) bth_lo[e] = lo;
}

// ---------------------------------------------------------------------------
// Kernel B (validated r3): xproj[r][n] = bf16(x[r][:]) @ btx^T + bias.
// Gate cols -> xp (stride XPST); q cols -> qx fp32 (if QX32) else inline.
// ---------------------------------------------------------------------------
template<typename XPT, bool QX32, int XPST>
__global__ __launch_bounds__(256) void xproj_gemm(
    const float* __restrict__ x, const ushortT* __restrict__ btx,
    const float* __restrict__ bi, const float* __restrict__ bg,
    const float* __restrict__ bo, const float* __restrict__ bfv,
    XPT* __restrict__ xp, float* __restrict__ qx)
{
  __shared__ ushortT As[128][72];   // +8 pad
  __shared__ ushortT Bs[128][72];
  const int tid = threadIdx.x;
  const int n0 = blockIdx.x * 128;
  const int m0 = blockIdx.y * 128;
  const int wid = tid >> 6, lane = tid & 63;
  const int nn = lane & 15, quad = lane >> 4;

  f32x4 acc[2][8];
  #pragma unroll
  for (int a = 0; a < 2; ++a)
    #pragma unroll
    for (int b = 0; b < 8; ++b) acc[a][b] = (f32x4){0.f,0.f,0.f,0.f};

  for (int kb = 0; kb < 8; ++kb){
    #pragma unroll
    for (int u = 0; u < 4; ++u){
      int idx = u*256 + tid;
      int r = idx >> 3, k8 = (idx & 7) * 8;
      const float* xa = &x[(size_t)(m0 + r) * I_ + kb*64 + k8];
      f32x4 f0 = *(const f32x4*)xa;
      f32x4 f1 = *(const f32x4*)(xa + 4);
      short8 av;
      #pragma unroll
      for (int i = 0; i < 4; ++i){ av[i] = (short)f2bf(f0[i]); av[4+i] = (short)f2bf(f1[i]); }
      *(short8*)&As[r][k8] = av;
      int ng = n0 + r;
      short8 bv = {0,0,0,0,0,0,0,0};
      if (ng < NTOT)
        bv = *(const short8*)&btx[(size_t)ng * 512 + kb*64 + k8];
      *(short8*)&Bs[r][k8] = bv;
    }
    __syncthreads();
    #pragma unroll
    for (int kc = 0; kc < 2; ++kc){
      int ko = kc*32 + quad*8;
      short8 a0 = *(const short8*)&As[wid*32 + nn][ko];
      short8 a1 = *(const short8*)&As[wid*32 + 16 + nn][ko];
      #pragma unroll
      for (int nt = 0; nt < 8; ++nt){
        short8 b = *(const short8*)&Bs[nt*16 + nn][ko];
        acc[0][nt] = __builtin_amdgcn_mfma_f32_16x16x32_bf16(a0, b, acc[0][nt], 0,0,0);
        acc[1][nt] = __builtin_amdgcn_mfma_f32_16x16x32_bf16(a1, b, acc[1][nt], 0,0,0);
      }
    }
    __syncthreads();
  }
  #pragma unroll
  for (int nt = 0; nt < 8; ++nt){
    int c = n0 + nt*16 + nn;
    if (c >= NTOT) continue;
    float bias;
    if (c < 512) bias = bi[c];
    else if (c < 1024) bias = bg[c - 512];
    else if (c < NG) bias = bo[c - 1024];
    else bias = bfv[c - NG];
    #pragma unroll
    for (int mt = 0; mt < 2; ++mt){
      int rb = m0 + wid*32 + mt*16 + quad*4;
      #pragma unroll
      for (int r = 0; r < 4; ++r){
        float v = acc[mt][nt][r] + bias;
        if (c < NG)
          stx(xp, (size_t)(rb + r) * XPST + c, v);
        else if (QX32)
          qx[(size_t)(rb + r) * 8 + (c - NG)] = v;
        else
          stx(xp, (size_t)(rb + r) * XPST + c, v);
      }
    }
  }
}

// ---------------------------------------------------------------------------
// Kernel C: persistent recurrence. 256 blocks (1/CU): g = blk&7 (16 batch
// rows), s = blk>>3 (16 H cols). Waves 0..2: i/g/o; wave 3: q. Weights
// LDS-resident. h exchanged via pre-split bf16 hi/lo staging, chunked layout
// [col_chunk][batch][16] (block-private 128B lines), parity ping-pong.
// Group barrier: release fetch_add / acquire spin, agent scope. c in regs.
// ---------------------------------------------------------------------------
template<typename XPT, bool QX32, bool WLO, int XPST>
__global__ __launch_bounds__(256) void qlstm_rec(
    float* __restrict__ dout, const float* __restrict__ h0,
    const float* __restrict__ c0,
    const ushortT* __restrict__ bth_hi, const ushortT* __restrict__ bth_lo,
    const XPT* __restrict__ xp, const float* __restrict__ qx,
    const float* __restrict__ Wfp, const float* __restrict__ bfp,
    const float* __restrict__ qa, const float* __restrict__ qbv,
    const float* __restrict__ qpar,
    ushortT* __restrict__ stg, unsigned int* __restrict__ cnt)
{
  __shared__ ushortT sWt[WLO ? 2 : 1][56][520];  // 520 stride: banks spread
  __shared__ float sGb[3][16][16];
  __shared__ float sQbuf[16][8];
  __shared__ float sWfp[8][16];
  __shared__ float sBfp[16];
  __shared__ float sQa[3], sQn[3], sQp[8];

  const int tid = threadIdx.x;
  const int g = blockIdx.x & 7, s = blockIdx.x >> 3;
  const int b0 = g * 16, j0 = s * 16;
  const int wid = tid >> 6, lane = tid & 63;
  const int nn = lane & 15, quad = lane >> 4;

  // one-time LDS weight staging (rows: 16 Wi | 16 Wg | 16 Wo | 8 Wf)
  for (int u = tid; u < 56*64; u += 256){
    int r = u >> 6, c8 = (u & 63) * 8;
    int src = (r < 48) ? ((r >> 4) * 512 + j0 + (r & 15)) : (NG + (r - 48));
    *(short8*)&sWt[0][r][c8] = *(const short8*)&bth_hi[(size_t)src * 512 + c8];
    if (WLO)
      *(short8*)&sWt[WLO?1:0][r][c8] = *(const short8*)&bth_lo[(size_t)src * 512 + c8];
  }
  if (tid < 128){ int nq = tid >> 4, jj = tid & 15; sWfp[nq][jj] = Wfp[nq*512 + j0 + jj]; }
  if (tid < 16) sBfp[tid] = bfp[j0 + tid];
  if (tid < 3){ sQa[tid] = qa[tid]; sQn[tid] = qbv[tid]; }
  if (tid < 8) sQp[tid] = qpar[tid];

  const int eb = tid >> 4, ej = tid & 15;
  const int jg = j0 + ej;
  float cst = c0[(size_t)(b0 + eb) * H_ + jg];

  const int wrow = (wid < 3) ? (wid*16 + nn) : (48 + (nn & 7));
  const int ncol = (wid < 3) ? (wid*512 + j0 + nn) : (NG + nn);
  const bool colok = (wid < 3) || (nn < 8);
  unsigned int* mycnt = cnt + (g << 9);
  bool dead = false;
  __syncthreads();

  for (int t = 0; t < T_; ++t){
    if (t > 0){
      if (tid == 0 && !dead){
        long it = 0;
        while (__hip_atomic_load(&mycnt[t-1], __ATOMIC_ACQUIRE,
                                 __HIP_MEMORY_SCOPE_AGENT) != 32u){
          __builtin_amdgcn_s_sleep(1);
          if (++it > 30000000L){ dead = true; break; }   // fail loud, not hung
        }
      }
      __syncthreads();
    }

    // xproj addends (issued early)
    float xpv[4];
    #pragma unroll
    for (int r = 0; r < 4; ++r){
      int b = quad*4 + r;
      if (!colok){ xpv[r] = 0.f; continue; }
      if (wid < 3)
        xpv[r] = ldx(xp, ((size_t)(b0 + b) * T_ + t) * XPST + ncol);
      else if (QX32)
        xpv[r] = qx[((size_t)(b0 + b) * T_ + t) * 8 + nn];
      else
        xpv[r] = ldx(xp, ((size_t)(b0 + b) * T_ + t) * XPST + ncol);
    }

    f32x4 acc = {0.f,0.f,0.f,0.f};
    if (t == 0){
      const float* arow = h0 + (size_t)(b0 + nn) * H_;
      #pragma unroll
      for (int kc = 0; kc < 16; ++kc){
        const float* ar = arow + kc*32 + quad*8;
        f32x4 h0v = *(const f32x4*)ar;
        f32x4 h1v = *(const f32x4*)(ar + 4);
        short8 ahi, alo;
        #pragma unroll
        for (int i = 0; i < 4; ++i){
          ushortT hi, lo;
          splitf(h0v[i], hi, lo); ahi[i] = (short)hi; alo[i] = (short)lo;
          splitf(h1v[i], hi, lo); ahi[4+i] = (short)hi; alo[4+i] = (short)lo;
        }
        short8 bhi = *(const short8*)&sWt[0][wrow][kc*32 + quad*8];
        if (WLO){
          short8 blo = *(const short8*)&sWt[WLO?1:0][wrow][kc*32 + quad*8];
          acc = __builtin_amdgcn_mfma_f32_16x16x32_bf16(alo, bhi, acc, 0,0,0);
          acc = __builtin_amdgcn_mfma_f32_16x16x32_bf16(ahi, blo, acc, 0,0,0);
        }
        acc = __builtin_amdgcn_mfma_f32_16x16x32_bf16(ahi, bhi, acc, 0,0,0);
      }
    } else {
      const int par = (t ^ 1) & 1;                 // parity of t-1
      const ushortT* shi = stg + (size_t)(0*2 + par) * 65536;
      const ushortT* slo = stg + (size_t)(1*2 + par) * 65536;
      #pragma unroll
      for (int kc = 0; kc < 16; ++kc){
        int off = (((kc*2 + (quad>>1))*128) + b0 + nn)*16 + (quad&1)*8;
        short8 ahi = *(const short8*)&shi[off];
        short8 bhi = *(const short8*)&sWt[0][wrow][kc*32 + quad*8];
        if (WLO){
          short8 alo = *(const short8*)&slo[off];
          short8 blo = *(const short8*)&sWt[WLO?1:0][wrow][kc*32 + quad*8];
          acc = __builtin_amdgcn_mfma_f32_16x16x32_bf16(alo, bhi, acc, 0,0,0);
          acc = __builtin_amdgcn_mfma_f32_16x16x32_bf16(ahi, blo, acc, 0,0,0);
        }
        acc = __builtin_amdgcn_mfma_f32_16x16x32_bf16(ahi, bhi, acc, 0,0,0);
      }
    }

    if (wid < 3){
      #pragma unroll
      for (int r = 0; r < 4; ++r){
        float v = acc[r] + xpv[r];
        v = (wid == 1) ? tanhfast(v) : sigf(v);
        sGb[wid][quad*4 + r][nn] = v;
      }
    } else if (nn < 8){
      float a0 = sQa[0], a1 = sQa[1], a2 = sQa[2];
      float n0v = sQn[0], n1 = sQn[1], n2 = sQn[2];
      float qp = sQp[nn];
      #pragma unroll
      for (int r = 0; r < 4; ++r){
        float v = acc[r] + xpv[r];
        v = tanhfast(v * a0 + n0v);
        v = tanhfast(v * a1 + n1);
        v = tanhfast(v * a2 + n2);
        sQbuf[quad*4 + r][nn] = v + qp;
      }
    }
    __syncthreads();

    float fpre = sBfp[ej];
    #pragma unroll
    for (int nq = 0; nq < 8; ++nq)
      fpre += sQbuf[eb][nq] * sWfp[nq][ej];
    float f = sigf(fpre);
    float iv = sGb[0][eb][ej], gv = sGb[1][eb][ej], ov = sGb[2][eb][ej];
    cst = f * cst + iv * gv;
    float hv = ov * tanhfast(cst);
    dout[((size_t)(b0 + eb) * T_ + t) * H_ + jg] = hv;
    ushortT hhi, hlo; splitf(hv, hhi, hlo);
    int so = ((s*128) + b0 + eb)*16 + ej;          // block-private 128B lines
    stg[(size_t)(0*2 + (t & 1)) * 65536 + so] = hhi;
    if (WLO) stg[(size_t)(1*2 + (t & 1)) * 65536 + so] = hlo;

    __syncthreads();   // each wave's s_waitcnt vmcnt(0) drains stores to L2
    if (tid == 0)
      __hip_atomic_fetch_add(&mycnt[t], 1u, __ATOMIC_RELEASE,
                             __HIP_MEMORY_SCOPE_AGENT);   // wbl2 -> agent-visible
  }
}

// ---------------------------------------------------------------------------
extern "C" void kernel_launch(void* const* d_in, const int* in_sizes, int n_in,
                              void* d_out, int out_size, void* d_ws, size_t ws_size,
                              hipStream_t stream)
{
  const float* x   = (const float*)d_in[0];
  const float* h0  = (const float*)d_in[1];
  const float* c0  = (const float*)d_in[2];
  const float* Wi  = (const float*)d_in[3];
  const float* bi  = (const float*)d_in[4];
  const float* Wg  = (const float*)d_in[5];
  const float* bg  = (const float*)d_in[6];
  const float* Wo  = (const float*)d_in[7];
  const float* bo  = (const float*)d_in[8];
  const float* Wf  = (const float*)d_in[9];
  const float* bfv = (const float*)d_in[10];
  const float* qa  = (const float*)d_in[11];
  const float* qb  = (const float*)d_in[12];
  const float* qp  = (const float*)d_in[13];
  const float* Wfp = (const float*)d_in[14];
  const float* bfp = (const float*)d_in[15];
  float* outp = (float*)d_out;

  const size_t R    = 65536;                     // B*T rows
  const size_t WB   = (size_t)NTOT * 512 * 2;    // bf16 weight block: 1,581,056 B
  const size_t QXB  = R * 8 * 4;                 // 2,097,152 B
  const size_t XP16 = R * NG * 2;                // 201,326,592 B
  const size_t XPF  = R * NTOT * 2;              // 202,375,168 B
  const size_t STGB = (size_t)4 * 128 * 512 * 2; // 524,288 B (hi/lo x parity)
  const size_t CNTB = (size_t)8 * 512 * 4;       // 16,384 B

  const size_t tA = XP16 + QXB + 3*WB;           // 208,166,912 B (<= r3 tier2)
  const size_t tB = XPF + 2*WB;                  // 205,537,280 B (== r3 tier3)

  char* ws = (char*)d_ws;

  if (ws_size >= tA){
    ushortT* xp     = (ushortT*)ws;
    float*   qx     = (float*)(ws + XP16);
    ushortT* btx    = (ushortT*)(ws + XP16 + QXB);
    ushortT* bth_hi = (ushortT*)(ws + XP16 + QXB + WB);
    ushortT* bth_lo = (ushortT*)(ws + XP16 + QXB + 2*WB);
    ushortT* stg    = btx;                       // btx dead after xproj
    unsigned int* cnt = (unsigned int*)((char*)btx + STGB);
    prep_w<<<dim3(3088), dim3(256), 0, stream>>>(Wi, Wg, Wo, Wf, btx, bth_hi, bth_lo, 1);
    xproj_gemm<ushortT, true, NG><<<dim3(13, 512), dim3(256), 0, stream>>>(
        x, btx, bi, bg, bo, bfv, xp, qx);
    hipMemsetAsync(cnt, 0, CNTB, stream);        // after xproj: btx region now free
    qlstm_rec<ushortT, true, true, NG><<<dim3(256), dim3(256), 0, stream>>>(
        outp, h0, c0, bth_hi, bth_lo, xp, qx, Wfp, bfp, qa, qb, qp, stg, cnt);
  } else if (ws_size >= tB){
    ushortT* xp     = (ushortT*)ws;
    ushortT* btx    = (ushortT*)(ws + XPF);
    ushortT* bth_hi = (ushortT*)(ws + XPF + WB);
    ushortT* stg    = btx;
    unsigned int* cnt = (unsigned int*)((char*)btx + STGB);
    prep_w<<<dim3(3088), dim3(256), 0, stream>>>(Wi, Wg, Wo, Wf, btx, bth_hi, bth_hi, 0);
    xproj_gemm<ushortT, false, NTOT><<<dim3(13, 512), dim3(256), 0, stream>>>(
        x, btx, bi, bg, bo, bfv, xp, nullptr);
    hipMemsetAsync(cnt, 0, CNTB, stream);
    qlstm_rec<ushortT, false, false, NTOT><<<dim3(256), dim3(256), 0, stream>>>(
        outp, h0, c0, bth_hi, bth_hi, xp, nullptr, Wfp, bfp, qa, qb, qp, stg, cnt);
  }
  // else: ws too small — leave out zeroed (fail loud with absmax = max|ref|)
}

// Round 5
// 5558.062 us; speedup vs baseline: 1.2807x; 1.2807x over previous
//
#include <hip/hip_runtime.h>
#include <stdint.h>

typedef unsigned short ushortT;
typedef unsigned long long u64T;
typedef __attribute__((ext_vector_type(8))) short short8;
typedef __attribute__((ext_vector_type(4))) float f32x4;

#define B_ 128
#define T_ 512
#define I_ 512
#define H_ 512
#define NG 1536     // 3*512 gate cols
#define NTOT 1544   // + 8 q cols

__device__ __forceinline__ float bf2f(ushortT u){
  union { unsigned int i; float f; } v; v.i = ((unsigned int)u) << 16; return v.f;
}
__device__ __forceinline__ ushortT f2bf(float f){           // RNE
  union { float f; unsigned int i; } v; v.f = f;
  unsigned int u = v.i;
  u += 0x7fffu + ((u >> 16) & 1u);
  return (ushortT)(u >> 16);
}
// truncating split: x == hi + lo to ~17 mantissa bits
__device__ __forceinline__ void splitf(float x, ushortT& hi, ushortT& lo){
  union { float f; unsigned int i; } v; v.f = x;
  hi = (ushortT)(v.i >> 16);
  union { unsigned int i; float f; } h; h.i = v.i & 0xffff0000u;
  union { float f; unsigned int i; } r; r.f = x - h.f;
  lo = (ushortT)(r.i >> 16);
}
__device__ __forceinline__ float sigf(float x){ return 1.f / (1.f + __expf(-x)); }
__device__ __forceinline__ float tanhfast(float x){
  float e = __expf(-2.f * fabsf(x));
  float t = (1.f - e) / (1.f + e);
  return copysignf(t, x);
}
__device__ __forceinline__ void stx(float* p, size_t i, float v){ p[i] = v; }
__device__ __forceinline__ void stx(ushortT* p, size_t i, float v){ p[i] = f2bf(v); }
__device__ __forceinline__ float ldx(const float* p, size_t i){ return p[i]; }
__device__ __forceinline__ float ldx(const ushortT* p, size_t i){ return bf2f(p[i]); }

// ---------------------------------------------------------------------------
// Kernel A (validated r3/r4): weight prep.
// ---------------------------------------------------------------------------
__global__ __launch_bounds__(256) void prep_w(
    const float* __restrict__ Wi, const float* __restrict__ Wg,
    const float* __restrict__ Wo, const float* __restrict__ Wf,
    ushortT* __restrict__ btx, ushortT* __restrict__ bth_hi,
    ushortT* __restrict__ bth_lo, int wlo)
{
  int e = blockIdx.x * 256 + threadIdx.x;   // 1544*512 = 3088*256
  int n = e >> 9;
  int k = e & 511;
  const float* W; int ld, c;
  if (n < 512){ W = Wi; ld = 512; c = n; }
  else if (n < 1024){ W = Wg; ld = 512; c = n - 512; }
  else if (n < 1536){ W = Wo; ld = 512; c = n - 1024; }
  else { W = Wf; ld = 8; c = n - 1536; }
  btx[e] = f2bf(W[(size_t)k * ld + c]);
  float wh = W[(size_t)(512 + k) * ld + c];
  ushortT hi, lo; splitf(wh, hi, lo);
  bth_hi[e] = hi;
  if (wlo) bth_lo[e] = lo;
}

// ---------------------------------------------------------------------------
// Kernel B (validated r3/r4): xproj.
// ---------------------------------------------------------------------------
template<typename XPT, bool QX32, int XPST>
__global__ __launch_bounds__(256) void xproj_gemm(
    const float* __restrict__ x, const ushortT* __restrict__ btx,
    const float* __restrict__ bi, const float* __restrict__ bg,
    const float* __restrict__ bo, const float* __restrict__ bfv,
    XPT* __restrict__ xp, float* __restrict__ qx)
{
  __shared__ ushortT As[128][72];   // +8 pad
  __shared__ ushortT Bs[128][72];
  const int tid = threadIdx.x;
  const int n0 = blockIdx.x * 128;
  const int m0 = blockIdx.y * 128;
  const int wid = tid >> 6, lane = tid & 63;
  const int nn = lane & 15, quad = lane >> 4;

  f32x4 acc[2][8];
  #pragma unroll
  for (int a = 0; a < 2; ++a)
    #pragma unroll
    for (int b = 0; b < 8; ++b) acc[a][b] = (f32x4){0.f,0.f,0.f,0.f};

  for (int kb = 0; kb < 8; ++kb){
    #pragma unroll
    for (int u = 0; u < 4; ++u){
      int idx = u*256 + tid;
      int r = idx >> 3, k8 = (idx & 7) * 8;
      const float* xa = &x[(size_t)(m0 + r) * I_ + kb*64 + k8];
      f32x4 f0 = *(const f32x4*)xa;
      f32x4 f1 = *(const f32x4*)(xa + 4);
      short8 av;
      #pragma unroll
      for (int i = 0; i < 4; ++i){ av[i] = (short)f2bf(f0[i]); av[4+i] = (short)f2bf(f1[i]); }
      *(short8*)&As[r][k8] = av;
      int ng = n0 + r;
      short8 bv = {0,0,0,0,0,0,0,0};
      if (ng < NTOT)
        bv = *(const short8*)&btx[(size_t)ng * 512 + kb*64 + k8];
      *(short8*)&Bs[r][k8] = bv;
    }
    __syncthreads();
    #pragma unroll
    for (int kc = 0; kc < 2; ++kc){
      int ko = kc*32 + quad*8;
      short8 a0 = *(const short8*)&As[wid*32 + nn][ko];
      short8 a1 = *(const short8*)&As[wid*32 + 16 + nn][ko];
      #pragma unroll
      for (int nt = 0; nt < 8; ++nt){
        short8 b = *(const short8*)&Bs[nt*16 + nn][ko];
        acc[0][nt] = __builtin_amdgcn_mfma_f32_16x16x32_bf16(a0, b, acc[0][nt], 0,0,0);
        acc[1][nt] = __builtin_amdgcn_mfma_f32_16x16x32_bf16(a1, b, acc[1][nt], 0,0,0);
      }
    }
    __syncthreads();
  }
  #pragma unroll
  for (int nt = 0; nt < 8; ++nt){
    int c = n0 + nt*16 + nn;
    if (c >= NTOT) continue;
    float bias;
    if (c < 512) bias = bi[c];
    else if (c < 1024) bias = bg[c - 512];
    else if (c < NG) bias = bo[c - 1024];
    else bias = bfv[c - NG];
    #pragma unroll
    for (int mt = 0; mt < 2; ++mt){
      int rb = m0 + wid*32 + mt*16 + quad*4;
      #pragma unroll
      for (int r = 0; r < 4; ++r){
        float v = acc[mt][nt][r] + bias;
        if (c < NG)
          stx(xp, (size_t)(rb + r) * XPST + c, v);
        else if (QX32)
          qx[(size_t)(rb + r) * 8 + (c - NG)] = v;
        else
          stx(xp, (size_t)(rb + r) * XPST + c, v);
      }
    }
  }
}

// ---------------------------------------------------------------------------
// Kernel C: persistent recurrence, MALL-coherent sync (RELAXED agent atomics
// only — no acquire/release => no per-step buffer_wbl2 / L2-invalidate).
// 256 blocks (1/CU): g = blk&7 (16 batch rows), s = blk>>3 (16 H cols).
// h exchanged through dout itself: producers store h with relaxed-agent u32
// stores (MALL-visible); consumers cooperatively load the group's 16x512 h
// into LDS (once per block, not once per wave) and split to bf16 hi/lo.
// Ordering: __syncthreads() drains vmcnt (store-acks) before the flag add.
// ---------------------------------------------------------------------------
template<typename XPT, bool QX32, bool WLO, int XPST>
__global__ __launch_bounds__(256) void qlstm_rec(
    float* __restrict__ dout, const float* __restrict__ h0,
    const float* __restrict__ c0,
    const ushortT* __restrict__ bth_hi, const ushortT* __restrict__ bth_lo,
    const XPT* __restrict__ xp, const float* __restrict__ qx,
    const float* __restrict__ Wfp, const float* __restrict__ bfp,
    const float* __restrict__ qa, const float* __restrict__ qbv,
    const float* __restrict__ qpar, unsigned int* __restrict__ cnt)
{
  __shared__ ushortT sWt[WLO ? 2 : 1][56][520];
  __shared__ float sH[16][516];      // 516: 16B-aligned rows, 2-way-ish banks
  __shared__ float sGb[3][16][16];
  __shared__ float sQbuf[16][8];
  __shared__ float sWfp[8][16];
  __shared__ float sBfp[16];
  __shared__ float sQa[3], sQn[3], sQp[8];

  const int tid = threadIdx.x;
  const int g = blockIdx.x & 7, s = blockIdx.x >> 3;
  const int b0 = g * 16, j0 = s * 16;
  const int wid = tid >> 6, lane = tid & 63;
  const int nn = lane & 15, quad = lane >> 4;

  // one-time LDS weight staging (rows: 16 Wi | 16 Wg | 16 Wo | 8 Wf)
  for (int u = tid; u < 56*64; u += 256){
    int r = u >> 6, c8 = (u & 63) * 8;
    int src = (r < 48) ? ((r >> 4) * 512 + j0 + (r & 15)) : (NG + (r - 48));
    *(short8*)&sWt[0][r][c8] = *(const short8*)&bth_hi[(size_t)src * 512 + c8];
    if (WLO)
      *(short8*)&sWt[WLO?1:0][r][c8] = *(const short8*)&bth_lo[(size_t)src * 512 + c8];
  }
  if (tid < 128){ int nq = tid >> 4, jj = tid & 15; sWfp[nq][jj] = Wfp[nq*512 + j0 + jj]; }
  if (tid < 16) sBfp[tid] = bfp[j0 + tid];
  if (tid < 3){ sQa[tid] = qa[tid]; sQn[tid] = qbv[tid]; }
  if (tid < 8) sQp[tid] = qpar[tid];

  const int eb = tid >> 4, ej = tid & 15;
  const int jg = j0 + ej;
  float cst = c0[(size_t)(b0 + eb) * H_ + jg];

  const int wrow = (wid < 3) ? (wid*16 + nn) : (48 + (nn & 7));
  const int ncol = (wid < 3) ? (wid*512 + j0 + nn) : (NG + nn);
  const bool colok = (wid < 3) || (nn < 8);
  unsigned int* mycnt = cnt + (g << 9);

  // cooperative h-loader mapping: row = tid>>4, lane-interleaved 8B columns
  const int lr = tid >> 4;
  const int lc0 = (tid & 15) * 2;          // float col base; +32 per iter
  const int lxs = (lr & 7) << 3;           // XOR swizzle (8-float chunks)
  const int rxs = (nn & 7) << 3;
  bool dead = false;
  __syncthreads();

  for (int t = 0; t < T_; ++t){
    // prefetch x-projection addends (independent of h -> hide behind spin)
    float xpv[4];
    #pragma unroll
    for (int r = 0; r < 4; ++r){
      int b = quad*4 + r;
      if (!colok){ xpv[r] = 0.f; continue; }
      if ((wid < 3) || !QX32)
        xpv[r] = ldx(xp, ((size_t)(b0 + b) * T_ + t) * XPST + ncol);
      else
        xpv[r] = qx[((size_t)(b0 + b) * T_ + t) * 8 + nn];
    }

    if (t > 0){
      if (tid == 0 && !dead){
        long it = 0;
        while (__hip_atomic_load(&mycnt[t-1], __ATOMIC_RELAXED,
                                 __HIP_MEMORY_SCOPE_AGENT) != 32u){
          __builtin_amdgcn_s_sleep(1);
          if (++it > 50000000L){ dead = true; break; }   // fail loud, not hung
        }
      }
      __syncthreads();
      const float* srow = dout + ((size_t)(b0 + lr) * T_ + (t - 1)) * H_;
      #pragma unroll
      for (int i = 0; i < 16; ++i){
        int c = lc0 + i*32;
        u64T v = __hip_atomic_load((const u64T*)(srow + c),
                                   __ATOMIC_RELAXED, __HIP_MEMORY_SCOPE_AGENT);
        *(u64T*)&sH[lr][c ^ lxs] = v;
      }
    } else {
      const float* srow = h0 + (size_t)(b0 + lr) * H_;
      #pragma unroll
      for (int i = 0; i < 16; ++i){
        int c = lc0 + i*32;
        *(u64T*)&sH[lr][c ^ lxs] = *(const u64T*)(srow + c);
      }
    }
    __syncthreads();

    f32x4 acc = {0.f,0.f,0.f,0.f};
    #pragma unroll
    for (int kc = 0; kc < 16; ++kc){
      const float* hp = &sH[nn][(kc*32 + quad*8) ^ rxs];
      f32x4 h0v = *(const f32x4*)hp;
      f32x4 h1v = *(const f32x4*)(hp + 4);
      short8 ahi, alo;
      #pragma unroll
      for (int i = 0; i < 4; ++i){
        ushortT hi, lo;
        splitf(h0v[i], hi, lo); ahi[i] = (short)hi; alo[i] = (short)lo;
        splitf(h1v[i], hi, lo); ahi[4+i] = (short)hi; alo[4+i] = (short)lo;
      }
      short8 bhi = *(const short8*)&sWt[0][wrow][kc*32 + quad*8];
      if (WLO){
        short8 blo = *(const short8*)&sWt[WLO?1:0][wrow][kc*32 + quad*8];
        acc = __builtin_amdgcn_mfma_f32_16x16x32_bf16(alo, bhi, acc, 0,0,0);
        acc = __builtin_amdgcn_mfma_f32_16x16x32_bf16(ahi, blo, acc, 0,0,0);
      }
      acc = __builtin_amdgcn_mfma_f32_16x16x32_bf16(ahi, bhi, acc, 0,0,0);
    }

    if (wid < 3){
      #pragma unroll
      for (int r = 0; r < 4; ++r){
        float v = acc[r] + xpv[r];
        v = (wid == 1) ? tanhfast(v) : sigf(v);
        sGb[wid][quad*4 + r][nn] = v;
      }
    } else if (nn < 8){
      float a0 = sQa[0], a1 = sQa[1], a2 = sQa[2];
      float n0v = sQn[0], n1 = sQn[1], n2 = sQn[2];
      float qp = sQp[nn];
      #pragma unroll
      for (int r = 0; r < 4; ++r){
        float v = acc[r] + xpv[r];
        v = tanhfast(v * a0 + n0v);
        v = tanhfast(v * a1 + n1);
        v = tanhfast(v * a2 + n2);
        sQbuf[quad*4 + r][nn] = v + qp;
      }
    }
    __syncthreads();

    float fpre = sBfp[ej];
    #pragma unroll
    for (int nq = 0; nq < 8; ++nq)
      fpre += sQbuf[eb][nq] * sWfp[nq][ej];
    float f = sigf(fpre);
    float iv = sGb[0][eb][ej], gv = sGb[1][eb][ej], ov = sGb[2][eb][ej];
    cst = f * cst + iv * gv;
    float hv = ov * tanhfast(cst);
    union { float f; unsigned int u; } hb; hb.f = hv;
    __hip_atomic_store(
        (unsigned int*)&dout[((size_t)(b0 + eb) * T_ + t) * H_ + jg], hb.u,
        __ATOMIC_RELAXED, __HIP_MEMORY_SCOPE_AGENT);   // MALL-visible, no wbl2

    __syncthreads();   // s_waitcnt vmcnt(0) before s_barrier: store-acks drained
    if (tid == 0 && !dead)
      __hip_atomic_fetch_add(&mycnt[t], 1u, __ATOMIC_RELAXED,
                             __HIP_MEMORY_SCOPE_AGENT);
  }
}

// ---------------------------------------------------------------------------
extern "C" void kernel_launch(void* const* d_in, const int* in_sizes, int n_in,
                              void* d_out, int out_size, void* d_ws, size_t ws_size,
                              hipStream_t stream)
{
  const float* x   = (const float*)d_in[0];
  const float* h0  = (const float*)d_in[1];
  const float* c0  = (const float*)d_in[2];
  const float* Wi  = (const float*)d_in[3];
  const float* bi  = (const float*)d_in[4];
  const float* Wg  = (const float*)d_in[5];
  const float* bg  = (const float*)d_in[6];
  const float* Wo  = (const float*)d_in[7];
  const float* bo  = (const float*)d_in[8];
  const float* Wf  = (const float*)d_in[9];
  const float* bfv = (const float*)d_in[10];
  const float* qa  = (const float*)d_in[11];
  const float* qb  = (const float*)d_in[12];
  const float* qp  = (const float*)d_in[13];
  const float* Wfp = (const float*)d_in[14];
  const float* bfp = (const float*)d_in[15];
  float* outp = (float*)d_out;

  const size_t R    = 65536;                     // B*T rows
  const size_t WB   = (size_t)NTOT * 512 * 2;    // bf16 weight block: 1,581,056 B
  const size_t QXB  = R * 8 * 4;                 // 2,097,152 B
  const size_t XP16 = R * NG * 2;                // 201,326,592 B
  const size_t XPF  = R * NTOT * 2;              // 202,375,168 B
  const size_t CNTB = (size_t)8 * 512 * 4;       // 16,384 B

  const size_t tA = XP16 + QXB + 3*WB;           // 208,166,912 B (r4-validated fit)
  const size_t tB = XPF + 2*WB;                  // 205,537,280 B

  char* ws = (char*)d_ws;

  if (ws_size >= tA){
    ushortT* xp     = (ushortT*)ws;
    float*   qx     = (float*)(ws + XP16);
    ushortT* btx    = (ushortT*)(ws + XP16 + QXB);
    ushortT* bth_hi = (ushortT*)(ws + XP16 + QXB + WB);
    ushortT* bth_lo = (ushortT*)(ws + XP16 + QXB + 2*WB);
    unsigned int* cnt = (unsigned int*)btx;      // btx dead after xproj
    prep_w<<<dim3(3088), dim3(256), 0, stream>>>(Wi, Wg, Wo, Wf, btx, bth_hi, bth_lo, 1);
    xproj_gemm<ushortT, true, NG><<<dim3(13, 512), dim3(256), 0, stream>>>(
        x, btx, bi, bg, bo, bfv, xp, qx);
    hipMemsetAsync(cnt, 0, CNTB, stream);        // stream-ordered: after xproj
    qlstm_rec<ushortT, true, true, NG><<<dim3(256), dim3(256), 0, stream>>>(
        outp, h0, c0, bth_hi, bth_lo, xp, qx, Wfp, bfp, qa, qb, qp, cnt);
  } else if (ws_size >= tB){
    ushortT* xp     = (ushortT*)ws;
    ushortT* btx    = (ushortT*)(ws + XPF);
    ushortT* bth_hi = (ushortT*)(ws + XPF + WB);
    unsigned int* cnt = (unsigned int*)btx;
    prep_w<<<dim3(3088), dim3(256), 0, stream>>>(Wi, Wg, Wo, Wf, btx, bth_hi, bth_hi, 0);
    xproj_gemm<ushortT, false, NTOT><<<dim3(13, 512), dim3(256), 0, stream>>>(
        x, btx, bi, bg, bo, bfv, xp, nullptr);
    hipMemsetAsync(cnt, 0, CNTB, stream);
    qlstm_rec<ushortT, false, false, NTOT><<<dim3(256), dim3(256), 0, stream>>>(
        outp, h0, c0, bth_hi, bth_hi, xp, nullptr, Wfp, bfp, qa, qb, qp, cnt);
  }
  // else: ws too small — leave out zeroed (fail loud with absmax = max|ref|)
}